// Round 10
// baseline (489.139 us; speedup 1.0000x reference)
//
#include <hip/hip_runtime.h>
#include <math.h>

#define STEPS 37
#define NMAT  (STEPS*STEPS + 1)   // 1370
#define D     128
#define NT    1024                // 16 waves, 4 per SIMD (hard VGPR cap 128)

typedef _Float16 half8 __attribute__((ext_vector_type(8)));
typedef __fp16   fp16x2 __attribute__((ext_vector_type(2)));
typedef float    f32x4 __attribute__((ext_vector_type(4)));

// Swizzled row-major fp16 matrices: 256B rows (128 halves), 16 slots of 16B,
// slot index XOR'd with (row&7)  -> conflict-free fragment reads (G4/T2).
#define PH_OFF   0          // P high;  later X row-major high  (A-operand)
#define PL_OFF   32768      // P low*2^11; later X row-major low
#define QTH_OFF  65536      // X^T high (B-operand, K-contiguous)
#define QTL_OFF  98304      // X^T low
#define RED_OFF  131072     // 512-float reduction scratch
#define PIV_OFF  (131072 + 2048)   // va,wa,vb,wb: 4 x 128 floats
#define SCAL_OFF (131072 + 4096)   // scalars
#define LDS_BYTES (131072 + 4096 + 64)

// Taylor 1/k!, degree 7 (theta = 0.5)
__constant__ float dC[8] = {
    1.0f, 1.0f, 5.0e-1f, 1.6666666666666666e-1f, 4.1666666666666664e-2f,
    8.3333333333333332e-3f, 1.3888888888888889e-3f, 1.9841269841269841e-4f };

__device__ __forceinline__ int swzA(int r, int slot) {       // 16B-slot address
    return r*256 + ((slot ^ (r & 7)) << 4);
}
__device__ __forceinline__ int swzE(int r, int c) {          // element address
    return r*256 + (((c >> 3) ^ (r & 7)) << 4) + ((c & 7) << 1);
}

// Y = A*X (+ diagc*I). A rows from PH/PL; X cols from QTH/QTL (X^T rows).
// 16 waves: (wr 0..3) x (wc 0..3) own rows [wr*32,+32) x cols [wc*32,+32).
template<bool WQT, bool WXR, bool WGL>
__device__ __forceinline__ void matmul_step(unsigned char* sm, float diagc,
                                            float* __restrict__ gout,
                                            int wr, int wc, int lr, int g)
{
    f32x4 acc1[2][2] = {};   // h*h
    f32x4 acc2[2][2] = {};   // h*l' + l'*h   (l' = l * 2^11)

    #pragma unroll
    for (int ks = 0; ks < 4; ++ks) {
        const int slot = 4*ks + g;             // 16B k-slot within a row
        half8 ah[2], al[2];
        #pragma unroll
        for (int bi = 0; bi < 2; ++bi) {
            const int r = wr*32 + bi*16 + lr;
            const int off = swzA(r, slot);
            ah[bi] = *(const half8*)(sm + PH_OFF + off);
            al[bi] = *(const half8*)(sm + PL_OFF + off);
        }
        #pragma unroll
        for (int bj = 0; bj < 2; ++bj) {
            const int c = wc*32 + bj*16 + lr;
            const int off = swzA(c, slot);
            const half8 qh = *(const half8*)(sm + QTH_OFF + off);
            const half8 ql = *(const half8*)(sm + QTL_OFF + off);
            #pragma unroll
            for (int bi = 0; bi < 2; ++bi) {
                acc1[bi][bj] = __builtin_amdgcn_mfma_f32_16x16x32_f16(ah[bi], qh, acc1[bi][bj], 0, 0, 0);
                acc2[bi][bj] = __builtin_amdgcn_mfma_f32_16x16x32_f16(ah[bi], ql, acc2[bi][bj], 0, 0, 0);
                acc2[bi][bj] = __builtin_amdgcn_mfma_f32_16x16x32_f16(al[bi], qh, acc2[bi][bj], 0, 0, 0);
            }
        }
    }

    if (WGL) {   // last step: stream fp32 to HBM, no LDS writes/barriers
        #pragma unroll
        for (int bi = 0; bi < 2; ++bi)
            #pragma unroll
            for (int bj = 0; bj < 2; ++bj) {
                const int col = wc*32 + bj*16 + lr;
                const int r0  = wr*32 + bi*16 + 4*g;
                #pragma unroll
                for (int q = 0; q < 4; ++q)
                    gout[(r0+q)*D + col] = acc1[bi][bj][q] + acc2[bi][bj][q] * (1.0f/2048.0f);
            }
        return;
    }

    // Register-only split conversion BEFORE the barrier (overlaps other waves' MFMAs)
    uint2 uhv[2][2], ulv[2][2];
    #pragma unroll
    for (int bi = 0; bi < 2; ++bi) {
        #pragma unroll
        for (int bj = 0; bj < 2; ++bj) {
            const int col = wc*32 + bj*16 + lr;
            const int r0  = wr*32 + bi*16 + 4*g;
            float v[4];
            #pragma unroll
            for (int q = 0; q < 4; ++q)
                v[q] = acc1[bi][bj][q] + acc2[bi][bj][q] * (1.0f/2048.0f);
            if (wr*32 + bi*16 == wc*32 + bj*16) {   // wave-uniform: tile holds diagonal
                #pragma unroll
                for (int q = 0; q < 4; ++q)
                    if (r0 + q == col) v[q] += diagc;
            }
            const fp16x2 h01 = __builtin_amdgcn_cvt_pkrtz(v[0], v[1]);
            const fp16x2 h23 = __builtin_amdgcn_cvt_pkrtz(v[2], v[3]);
            const fp16x2 l01 = __builtin_amdgcn_cvt_pkrtz((v[0]-(float)h01[0])*2048.f,
                                                          (v[1]-(float)h01[1])*2048.f);
            const fp16x2 l23 = __builtin_amdgcn_cvt_pkrtz((v[2]-(float)h23[0])*2048.f,
                                                          (v[3]-(float)h23[1])*2048.f);
            union { fp16x2 h2[2]; uint2 u; } cvh, cvl;
            cvh.h2[0] = h01; cvh.h2[1] = h23;
            cvl.h2[0] = l01; cvl.h2[1] = l23;
            uhv[bi][bj] = cvh.u; ulv[bi][bj] = cvl.u;
        }
    }
    __syncthreads();   // all reads of P/X done before overwrite

    #pragma unroll
    for (int bi = 0; bi < 2; ++bi) {
        #pragma unroll
        for (int bj = 0; bj < 2; ++bj) {
            const int col = wc*32 + bj*16 + lr;
            const int r0  = wr*32 + bi*16 + 4*g;
            if (WQT) {   // X^T: b64 at row=col, k-halves r0..r0+3 (swizzled slot)
                const int off = col*256 + (((r0 >> 3) ^ (col & 7)) << 4) + ((g & 1) << 3);
                *(uint2*)(sm + QTH_OFF + off) = uhv[bi][bj];
                *(uint2*)(sm + QTL_OFF + off) = ulv[bi][bj];
            }
            if (WXR) {   // X row-major: scattered u16 (transpose cost)
                union { uint2 u; _Float16 h[4]; } th, tl;
                th.u = uhv[bi][bj]; tl.u = ulv[bi][bj];
                #pragma unroll
                for (int q = 0; q < 4; ++q) {
                    const int rr = r0 + q;
                    const int off = swzE(rr, col);
                    *(_Float16*)(sm + PH_OFF + off) = th.h[q];
                    *(_Float16*)(sm + PL_OFF + off) = tl.h[q];
                }
            }
        }
    }
    __syncthreads();   // writes visible before next step's reads
}

__global__ __launch_bounds__(NT)
void liere_expm_mfma(const float* __restrict__ gen, float* __restrict__ out)
{
    __shared__ __align__(16) unsigned char sm[LDS_BYTES];
    const int tid = threadIdx.x;
    const int wg  = blockIdx.x;

    float px = 0.f, py = 0.f;
    if (wg > 0) {
        const int idx = wg - 1;
        px = (float)(idx / STEPS) * (1.0f/(STEPS-1));
        py = (float)(idx % STEPS) * (1.0f/(STEPS-1));
    }

    // ---- Phase 0: G = px*S0 + py*S1 (fp32), padded 132-float rows at sm+0
    float* Gp = (float*)sm;
    const float* g0 = gen;
    const float* g1 = gen + D*D;
    #pragma unroll
    for (int it = 0; it < 16; ++it) {
        const int e = tid + (it << 10);
        const int i = e >> 7, j = e & 127;
        if (i < j) {
            const float v = px*g0[e] + py*g1[e];
            Gp[i*132 + j] =  v;
            Gp[j*132 + i] = -v;
        } else if (i == j) {
            Gp[i*132 + j] = 0.f;
        }
    }
    __syncthreads();

    float* red  = (float*)(sm + RED_OFF);
    float* va   = (float*)(sm + PIV_OFF);
    float* wa   = (float*)(sm + PIV_OFF + 512);
    float* vb   = (float*)(sm + PIV_OFF + 1024);
    float* wb   = (float*)(sm + PIV_OFF + 1536);
    float* scal = (float*)(sm + SCAL_OFF);

    // ---- Phase 1a: 1-norm (row abs-sums -> max); also init power-iter seeds
    if (tid < D) {
        float s = 0.f;
        const f32x4* rowp = (const f32x4*)&Gp[tid*132];
        #pragma unroll 8
        for (int u = 0; u < 32; ++u) {
            const f32x4 v = rowp[u];
            s += fabsf(v.x) + fabsf(v.y) + fabsf(v.z) + fabsf(v.w);
        }
        red[tid] = s;
        va[tid] = 0.5f + (float)((tid * 2654435761u) >> 24) * (1.0f/256.0f);
        vb[tid] = 0.5f + (float)((tid * 1597334677u) >> 24) * (1.0f/256.0f);
    }
    __syncthreads();
    if (tid < 64) {
        float a = fmaxf(red[tid], red[tid + 64]);
        a = fmaxf(a, __shfl_xor(a, 32)); a = fmaxf(a, __shfl_xor(a, 16));
        a = fmaxf(a, __shfl_xor(a, 8));  a = fmaxf(a, __shfl_xor(a, 4));
        a = fmaxf(a, __shfl_xor(a, 2));  a = fmaxf(a, __shfl_xor(a, 1));
        if (tid == 0) scal[0] = a;
    }
    __syncthreads();

    // ---- Phase 1b: dual power iteration, 6 matvecs each (concurrent runs).
    // sigma_est = ||G u5|| / ||u5|| <= sigma_true (never over-estimates).
    {
        const int i = tid >> 3, p = tid & 7;
        const float* row = &Gp[i*132 + p*16];
        #pragma unroll
        for (int itm = 0; itm < 6; ++itm) {
            const float* sa = (itm & 1) ? wa : va;
            const float* sb = (itm & 1) ? wb : vb;
            float* da = (itm & 1) ? va : wa;
            float* db = (itm & 1) ? vb : wb;
            float pa = 0.f, pb = 0.f;
            #pragma unroll
            for (int u = 0; u < 16; ++u) {
                const float gv = row[u];
                pa += gv * sa[p*16 + u];
                pb += gv * sb[p*16 + u];
            }
            pa += __shfl_xor(pa, 4); pa += __shfl_xor(pa, 2); pa += __shfl_xor(pa, 1);
            pb += __shfl_xor(pb, 4); pb += __shfl_xor(pb, 2); pb += __shfl_xor(pb, 1);
            if (p == 0) { da[i] = pa; db[i] = pb; }
            __syncthreads();
        }
    }
    // u5 in wa/wb, u6 in va/vb: four squared-norm partials, one combined reduce
    if (tid < D) {
        red[tid]       = wa[tid]*wa[tid];
        red[128 + tid] = va[tid]*va[tid];
        red[256 + tid] = wb[tid]*wb[tid];
        red[384 + tid] = vb[tid]*vb[tid];
    }
    __syncthreads();
    if (tid < 256) {
        const int grp = tid >> 6, l = tid & 63;
        float a = red[grp*128 + l] + red[grp*128 + l + 64];
        a += __shfl_xor(a, 32); a += __shfl_xor(a, 16); a += __shfl_xor(a, 8);
        a += __shfl_xor(a, 4);  a += __shfl_xor(a, 2);  a += __shfl_xor(a, 1);
        if (l == 0) scal[1 + grp] = a;
    }
    __syncthreads();

    const float m1  = scal[0];
    const float n5a = scal[1], n6a = scal[2], n5b = scal[3], n6b = scal[4];
    int s1 = 0;
    if (m1 > 0.5f) { s1 = (int)ceilf(log2f(m1 * 2.0f)); if (s1 < 0) s1 = 0; }
    const float sea = (n5a > 1e-20f) ? sqrtf(n6a / n5a) : 0.f;
    const float seb = (n5b > 1e-20f) ? sqrtf(n6b / n5b) : 0.f;
    const float sg  = fmaxf(sea, seb) * 1.25f;          // safety margin
    int nsq = 0;
    if (sg > 0.5f) { nsq = (int)ceilf(log2f(sg * 2.0f)); if (nsq < 0) nsq = 0; }
    int lo = s1 - 3; if (lo < 0) lo = 0;                // estimator-failure floor
    if (nsq < lo) nsq = lo;
    if (nsq > s1) nsq = s1;                             // never exceed 1-norm count
    const float scale = exp2f(-(float)nsq);

    // ---- Phase A: stash this lane's G values (regions about to be reused)
    float vst[16];
    #pragma unroll
    for (int it = 0; it < 16; ++it) {
        const int e = tid + (it << 10);
        vst[it] = Gp[(e>>7)*132 + (e&127)];
    }
    __syncthreads();

    // ---- Phase B: split P = G*2^-s into fp16 (h, l*2^11); init X = c7*P + c6*I
    {
        const float c7 = dC[7], c6 = dC[6];
        #pragma unroll
        for (int it = 0; it < 16; ++it) {
            const int e = tid + (it << 10);
            const int i = e >> 7, j = e & 127;
            const float p = vst[it] * scale;
            const _Float16 ph = (_Float16)p;
            const _Float16 pl = (_Float16)((p - (float)ph) * 2048.f);
            const int offP = swzE(i, j);
            *(_Float16*)(sm + PH_OFF + offP) = ph;
            *(_Float16*)(sm + PL_OFF + offP) = pl;
            const float x = c7*p + ((i == j) ? c6 : 0.f);
            const _Float16 xh = (_Float16)x;
            const _Float16 xl = (_Float16)((x - (float)xh) * 2048.f);
            const int offQ = swzE(j, i);           // X^T
            *(_Float16*)(sm + QTH_OFF + offQ) = xh;
            *(_Float16*)(sm + QTL_OFF + offQ) = xl;
        }
    }
    __syncthreads();

    const int lid = tid & 63;
    const int wid = tid >> 6;          // 0..15
    const int wr = wid >> 2, wc = wid & 3;
    const int lr = lid & 15, g = lid >> 4;
    float* gout = out + (size_t)wg * (D*D);

    // ---- Horner: X <- P*X + c_k*I (degree-7 Taylor, theta=0.5): 6 muls
    for (int kk = 5; kk >= 1; --kk)
        matmul_step<true, false, false>(sm, dC[kk], gout, wr, wc, lr, g);
    matmul_step<true, true, false>(sm, dC[0], gout, wr, wc, lr, g);

    if (nsq == 0) {   // tiny-norm blocks (incl. CLS)
        #pragma unroll
        for (int it = 0; it < 16; ++it) {
            const int e = tid + (it << 10);
            const int i = e >> 7, j = e & 127;
            const int off = swzE(i, j);
            gout[e] = (float)*(_Float16*)(sm + PH_OFF + off)
                    + (float)*(_Float16*)(sm + PL_OFF + off) * (1.0f/2048.0f);
        }
        return;
    }

    // ---- Squarings: X <- X*X; last one streams fp32 straight to HBM
    for (int t = 0; t < nsq - 1; ++t)
        matmul_step<true, true, false>(sm, 0.f, gout, wr, wc, lr, g);
    matmul_step<false, false, true>(sm, 0.f, gout, wr, wc, lr, g);
}

extern "C" void kernel_launch(void* const* d_in, const int* in_sizes, int n_in,
                              void* d_out, int out_size, void* d_ws, size_t ws_size,
                              hipStream_t stream) {
    (void)in_sizes; (void)n_in; (void)d_ws; (void)ws_size; (void)out_size;
    const float* gen = (const float*)d_in[1];   // [2,1,128,128] fp32
    float* out = (float*)d_out;                 // [1,1370,1,128,128] fp32
    liere_expm_mfma<<<NMAT, NT, 0, stream>>>(gen, out);
}